// Round 1
// baseline (1296.600 us; speedup 1.0000x reference)
//
#include <hip/hip_runtime.h>
#include <hip/hip_bf16.h>
#include <cstdint>

// ---------------------------------------------------------------------------
// GCN 3-layer forward: h = relu(Â (h W) + b) x3, mean-pool, final linear.
// Â built once per launch as CSR-by-destination; aggregation is a gather
// (one wave per node), no float atomics on feature data.
// ---------------------------------------------------------------------------

// Detect whether edge_index arrived as int64 (odd int32 words all zero) or
// int32. Writes mode[0] = 1 for int64, 0 for int32.
__global__ void k_detect(const int* __restrict__ ei, int* __restrict__ mode, int e) {
  __shared__ int any;
  if (threadIdx.x == 0) any = 0;
  __syncthreads();
  int lim = min(e, 2048);
  int local = 0;
  for (int i = threadIdx.x; i < lim; i += blockDim.x)
    local |= (ei[2 * i + 1] != 0);
  if (local) atomicOr(&any, 1);
  __syncthreads();
  if (threadIdx.x == 0) mode[0] = (any == 0) ? 1 : 0;
}

__global__ void k_zero(int* __restrict__ count, float* __restrict__ pooled, int n) {
  int i = blockIdx.x * blockDim.x + threadIdx.x;
  if (i < n) count[i] = 0;
  if (i < 128) pooled[i] = 0.0f;
}

__global__ void k_hist(const int* __restrict__ ei, const int* __restrict__ mode,
                       int* __restrict__ count, int e) {
  int i = blockIdx.x * blockDim.x + threadIdx.x;
  if (i >= e) return;
  int m = mode[0];
  long long di = (long long)e + i;
  int d = m ? ei[2 * di] : ei[di];
  atomicAdd(&count[d], 1);
}

// Single-block exclusive scan over N bins; also emits cursor copy and
// dis[n] = rsqrt(deg_in + 1 self-loop).
__global__ __launch_bounds__(1024) void k_scan(const int* __restrict__ count,
                                               int* __restrict__ offs,
                                               int* __restrict__ cursor,
                                               float* __restrict__ dis,
                                               int n, int total) {
  __shared__ int part[1024];
  int t = threadIdx.x;
  int chunk = (n + 1023) >> 10;
  int lo = t * chunk;
  int hi = min(n, lo + chunk);
  int s = 0;
  for (int i = lo; i < hi; ++i) s += count[i];
  part[t] = s;
  __syncthreads();
  for (int d = 1; d < 1024; d <<= 1) {
    int v = (t >= d) ? part[t - d] : 0;
    __syncthreads();
    part[t] += v;
    __syncthreads();
  }
  int run = (t == 0) ? 0 : part[t - 1];
  for (int i = lo; i < hi; ++i) {
    offs[i] = run;
    cursor[i] = run;
    dis[i] = rsqrtf((float)count[i] + 1.0f);
    run += count[i];
  }
  if (t == 0) offs[n] = total;
}

__global__ void k_fill(const int* __restrict__ ei, const int* __restrict__ mode,
                       int* __restrict__ cursor, int* __restrict__ csr, int e) {
  int i = blockIdx.x * blockDim.x + threadIdx.x;
  if (i >= e) return;
  int m = mode[0];
  long long di = (long long)e + i;
  int s = m ? ei[2 * (long long)i] : ei[i];
  int d = m ? ei[2 * di] : ei[di];
  int pos = atomicAdd(&cursor[d], 1);
  csr[pos] = s;
}

// tmp[r,:] = dis[r] * (h[r,:] @ W)   (128x128 weight staged in LDS;
// h tile staged transposed hs[128][32] -> conflict-free broadcast reads)
__global__ __launch_bounds__(256) void k_gemm_scale(const float* __restrict__ h,
                                                    const float* __restrict__ W,
                                                    const float* __restrict__ dis,
                                                    float* __restrict__ tmp, int n) {
  __shared__ float Ws[128 * 128];   // 64 KB
  __shared__ float hs[128 * 32];    // 16 KB (transposed: hs[k][r])
  const int tid = threadIdx.x;

  for (int i = tid * 4; i < 128 * 128; i += 256 * 4)
    *reinterpret_cast<float4*>(&Ws[i]) = *reinterpret_cast<const float4*>(&W[i]);

  const int row0 = blockIdx.x * 32;
  for (int i = tid; i < 32 * 128; i += 256) {
    int r = i >> 7, c = i & 127;
    int gr = row0 + r;
    hs[(c << 5) + r] = (gr < n) ? h[(size_t)gr * 128 + c] : 0.0f;
  }
  __syncthreads();

  const int r = tid & 31;          // row within tile
  const int j0 = (tid >> 5) * 16;  // 16 output cols per thread
  float4 a0 = {0, 0, 0, 0}, a1 = {0, 0, 0, 0}, a2 = {0, 0, 0, 0}, a3 = {0, 0, 0, 0};

#pragma unroll 4
  for (int k = 0; k < 128; ++k) {
    float hv = hs[(k << 5) + r];
    const float4* wr = reinterpret_cast<const float4*>(&Ws[(k << 7) + j0]);
    float4 w0 = wr[0], w1 = wr[1], w2 = wr[2], w3 = wr[3];
    a0.x = fmaf(hv, w0.x, a0.x); a0.y = fmaf(hv, w0.y, a0.y);
    a0.z = fmaf(hv, w0.z, a0.z); a0.w = fmaf(hv, w0.w, a0.w);
    a1.x = fmaf(hv, w1.x, a1.x); a1.y = fmaf(hv, w1.y, a1.y);
    a1.z = fmaf(hv, w1.z, a1.z); a1.w = fmaf(hv, w1.w, a1.w);
    a2.x = fmaf(hv, w2.x, a2.x); a2.y = fmaf(hv, w2.y, a2.y);
    a2.z = fmaf(hv, w2.z, a2.z); a2.w = fmaf(hv, w2.w, a2.w);
    a3.x = fmaf(hv, w3.x, a3.x); a3.y = fmaf(hv, w3.y, a3.y);
    a3.z = fmaf(hv, w3.z, a3.z); a3.w = fmaf(hv, w3.w, a3.w);
  }

  int gr = row0 + r;
  if (gr < n) {
    float dn = dis[gr];
    a0.x *= dn; a0.y *= dn; a0.z *= dn; a0.w *= dn;
    a1.x *= dn; a1.y *= dn; a1.z *= dn; a1.w *= dn;
    a2.x *= dn; a2.y *= dn; a2.z *= dn; a2.w *= dn;
    a3.x *= dn; a3.y *= dn; a3.z *= dn; a3.w *= dn;
    float4* o = reinterpret_cast<float4*>(&tmp[(size_t)gr * 128 + j0]);
    o[0] = a0; o[1] = a1; o[2] = a2; o[3] = a3;
  }
}

// h_out[d,:] = relu(dis[d] * (sum_{src in-edges} tmp[src,:] + tmp[d,:]) + b)
// one 64-lane wave per node, float2 per lane (512B per row access).
__global__ __launch_bounds__(256) void k_gather(const float* __restrict__ tmp,
                                                const int* __restrict__ csr,
                                                const int* __restrict__ offs,
                                                const float* __restrict__ dis,
                                                const float* __restrict__ bias,
                                                float* __restrict__ hout, int n) {
  int node = blockIdx.x * 4 + (threadIdx.x >> 6);
  if (node >= n) return;
  int lane = threadIdx.x & 63;
  int c = lane * 2;
  int s0 = offs[node], s1 = offs[node + 1];

  float ax = 0.f, ay = 0.f, bx = 0.f, by = 0.f;
  int e = s0;
  for (; e + 1 < s1; e += 2) {
    int sA = csr[e], sB = csr[e + 1];
    float2 vA = *reinterpret_cast<const float2*>(&tmp[(size_t)sA * 128 + c]);
    float2 vB = *reinterpret_cast<const float2*>(&tmp[(size_t)sB * 128 + c]);
    ax += vA.x; ay += vA.y; bx += vB.x; by += vB.y;
  }
  if (e < s1) {
    int sA = csr[e];
    float2 vA = *reinterpret_cast<const float2*>(&tmp[(size_t)sA * 128 + c]);
    ax += vA.x; ay += vA.y;
  }
  float2 sv = *reinterpret_cast<const float2*>(&tmp[(size_t)node * 128 + c]);
  ax += bx + sv.x;
  ay += by + sv.y;

  float dn = dis[node];
  float2 bb = *reinterpret_cast<const float2*>(&bias[c]);
  float rx = fmaf(dn, ax, bb.x);
  float ry = fmaf(dn, ay, bb.y);
  rx = rx > 0.f ? rx : 0.f;
  ry = ry > 0.f ? ry : 0.f;
  float2 res; res.x = rx; res.y = ry;
  *reinterpret_cast<float2*>(&hout[(size_t)node * 128 + c]) = res;
}

// column sums of h -> pooled[128] (block-local reduce, 128 atomics/block)
__global__ __launch_bounds__(256) void k_pool(const float* __restrict__ h,
                                              float* __restrict__ pooled, int n) {
  int col = threadIdx.x & 127;
  int half = threadIdx.x >> 7;
  float acc = 0.f;
  for (int r = blockIdx.x * 2 + half; r < n; r += gridDim.x * 2)
    acc += h[(size_t)r * 128 + col];
  __shared__ float red[256];
  red[threadIdx.x] = acc;
  __syncthreads();
  if (threadIdx.x < 128)
    atomicAdd(&pooled[threadIdx.x], red[threadIdx.x] + red[threadIdx.x + 128]);
}

__global__ void k_final(const float* __restrict__ pooled, const float* __restrict__ Wfc,
                        const float* __restrict__ bfc, float* __restrict__ out,
                        float invn) {
  int j = threadIdx.x;
  if (j < 32) {
    float acc = 0.f;
    for (int k = 0; k < 128; ++k) acc = fmaf(pooled[k], Wfc[k * 32 + j], acc);
    out[j] = fmaf(acc, invn, bfc[j]);
  }
}

extern "C" void kernel_launch(void* const* d_in, const int* in_sizes, int n_in,
                              void* d_out, int out_size, void* d_ws, size_t ws_size,
                              hipStream_t stream) {
  const float* x   = (const float*)d_in[0];
  const int*   ei  = (const int*)d_in[1];
  const float* W0  = (const float*)d_in[2];
  const float* b0  = (const float*)d_in[3];
  const float* W1  = (const float*)d_in[4];
  const float* b1  = (const float*)d_in[5];
  const float* W2  = (const float*)d_in[6];
  const float* b2  = (const float*)d_in[7];
  const float* Wfc = (const float*)d_in[8];
  const float* bfc = (const float*)d_in[9];

  const int n = in_sizes[0] / 128;
  const int e = in_sizes[1] / 2;

  char* ws = (char*)d_ws;
  size_t off = 0;
  auto alloc = [&](size_t bytes) -> void* {
    void* p = ws + off;
    off = (off + bytes + 255) & ~(size_t)255;
    return p;
  };
  int*   mode   = (int*)alloc(sizeof(int));
  int*   count  = (int*)alloc((size_t)n * 4);
  int*   offs   = (int*)alloc((size_t)(n + 1) * 4);
  int*   cursor = (int*)alloc((size_t)n * 4);
  float* dis    = (float*)alloc((size_t)n * 4);
  int*   csr    = (int*)alloc((size_t)e * 4);
  float* pooled = (float*)alloc(128 * 4);
  float* bufA   = (float*)alloc((size_t)n * 128 * 4);
  float* bufB   = (float*)alloc((size_t)n * 128 * 4);

  int gz = (n + 255) / 256;
  int ge = (e + 255) / 256;

  k_detect<<<1, 256, 0, stream>>>(ei, mode, e);
  k_zero<<<gz, 256, 0, stream>>>(count, pooled, n);
  k_hist<<<ge, 256, 0, stream>>>(ei, mode, count, e);
  k_scan<<<1, 1024, 0, stream>>>(count, offs, cursor, dis, n, e);
  k_fill<<<ge, 256, 0, stream>>>(ei, mode, cursor, csr, e);

  const float* Ws_[3] = {W0, W1, W2};
  const float* bs_[3] = {b0, b1, b2};
  const float* hin = x;
  int gg = (n + 31) / 32;
  int gn = (n + 3) / 4;
  for (int l = 0; l < 3; ++l) {
    k_gemm_scale<<<gg, 256, 0, stream>>>(hin, Ws_[l], dis, bufB, n);
    k_gather<<<gn, 256, 0, stream>>>(bufB, csr, offs, dis, bs_[l], bufA, n);
    hin = bufA;
  }

  k_pool<<<256, 256, 0, stream>>>(bufA, pooled, n);
  k_final<<<1, 32, 0, stream>>>(pooled, Wfc, bfc, (float*)d_out, 1.0f / (float)n);
}

// Round 2
// 881.679 us; speedup vs baseline: 1.4706x; 1.4706x over previous
//
#include <hip/hip_runtime.h>
#include <hip/hip_bf16.h>
#include <cstdint>

// ---------------------------------------------------------------------------
// GCN 3-layer forward: h = relu(Â (h W) + b) x3, mean-pool, final linear.
// Â built once per launch as CSR-by-destination; aggregation is a gather
// (one wave per node), no float atomics on feature data.
// R2: hierarchical scan (was 281us single-block), 4x4 register-blocked GEMM,
//     gather ILP x4.
// ---------------------------------------------------------------------------

// Detect whether edge_index arrived as int64 (odd int32 words all zero) or
// int32. Writes mode[0] = 1 for int64, 0 for int32.
__global__ void k_detect(const int* __restrict__ ei, int* __restrict__ mode, int e) {
  __shared__ int any;
  if (threadIdx.x == 0) any = 0;
  __syncthreads();
  int lim = min(e, 2048);
  int local = 0;
  for (int i = threadIdx.x; i < lim; i += blockDim.x)
    local |= (ei[2 * i + 1] != 0);
  if (local) atomicOr(&any, 1);
  __syncthreads();
  if (threadIdx.x == 0) mode[0] = (any == 0) ? 1 : 0;
}

__global__ void k_zero(int* __restrict__ count, float* __restrict__ pooled, int n) {
  int i = blockIdx.x * blockDim.x + threadIdx.x;
  if (i < n) count[i] = 0;
  if (i < 128) pooled[i] = 0.0f;
}

__global__ void k_hist(const int* __restrict__ ei, const int* __restrict__ mode,
                       int* __restrict__ count, int e) {
  int i = blockIdx.x * blockDim.x + threadIdx.x;
  if (i >= e) return;
  int m = mode[0];
  long long di = (long long)e + i;
  int d = m ? ei[2 * di] : ei[di];
  atomicAdd(&count[d], 1);
}

// --- hierarchical exclusive scan over count[n] ------------------------------
// scan1: per-block (1024 elems) sums. scan2: 1-block scan of block sums.
// scan3: local scan + base, writes offs/cursor/dis.

__global__ __launch_bounds__(256) void k_scan1(const int* __restrict__ count,
                                               int* __restrict__ bsum, int n) {
  int base = blockIdx.x * 1024 + threadIdx.x * 4;
  int s = 0;
#pragma unroll
  for (int j = 0; j < 4; ++j) {
    int i = base + j;
    if (i < n) s += count[i];
  }
  __shared__ int red[256];
  red[threadIdx.x] = s;
  __syncthreads();
  for (int d = 128; d > 0; d >>= 1) {
    if (threadIdx.x < d) red[threadIdx.x] += red[threadIdx.x + d];
    __syncthreads();
  }
  if (threadIdx.x == 0) bsum[blockIdx.x] = red[0];
}

__global__ __launch_bounds__(1024) void k_scan2(int* __restrict__ bsum, int nb) {
  __shared__ int sh[1024];
  int t = threadIdx.x;
  sh[t] = (t < nb) ? bsum[t] : 0;
  __syncthreads();
  for (int d = 1; d < 1024; d <<= 1) {
    int u = (t >= d) ? sh[t - d] : 0;
    __syncthreads();
    sh[t] += u;
    __syncthreads();
  }
  if (t < nb) bsum[t] = (t == 0) ? 0 : sh[t - 1];  // exclusive
}

__global__ __launch_bounds__(256) void k_scan3(const int* __restrict__ count,
                                               const int* __restrict__ bsum,
                                               int* __restrict__ offs,
                                               int* __restrict__ cursor,
                                               float* __restrict__ dis,
                                               int n, int total) {
  __shared__ int red[256];
  int t = threadIdx.x;
  int base = blockIdx.x * 1024 + t * 4;
  int c[4];
  int s = 0;
#pragma unroll
  for (int j = 0; j < 4; ++j) {
    int i = base + j;
    c[j] = (i < n) ? count[i] : 0;
    s += c[j];
  }
  red[t] = s;
  __syncthreads();
  for (int d = 1; d < 256; d <<= 1) {
    int u = (t >= d) ? red[t - d] : 0;
    __syncthreads();
    red[t] += u;
    __syncthreads();
  }
  int run = bsum[blockIdx.x] + ((t == 0) ? 0 : red[t - 1]);
#pragma unroll
  for (int j = 0; j < 4; ++j) {
    int i = base + j;
    if (i < n) {
      offs[i] = run;
      cursor[i] = run;
      dis[i] = rsqrtf((float)c[j] + 1.0f);
      run += c[j];
    }
  }
  if (blockIdx.x == 0 && t == 0) offs[n] = total;
}

__global__ void k_fill(const int* __restrict__ ei, const int* __restrict__ mode,
                       int* __restrict__ cursor, int* __restrict__ csr, int e) {
  int i = blockIdx.x * blockDim.x + threadIdx.x;
  if (i >= e) return;
  int m = mode[0];
  long long di = (long long)e + i;
  int s = m ? ei[2 * (long long)i] : ei[i];
  int d = m ? ei[2 * di] : ei[di];
  int pos = atomicAdd(&cursor[d], 1);
  csr[pos] = s;
}

// tmp[r,:] = dis[r] * (h[r,:] @ W)
// 32-row tile, 256 threads, 4x4 microtile per thread.
// hs stored transposed [k][32] with XOR swizzle (r ^ 4*(k&7)) so the staging
// write is ~8-way instead of 64-way conflicted while reads stay contiguous
// 16B-aligned float4 (XOR by multiple of 4 permutes within aligned quads).
__global__ __launch_bounds__(256) void k_gemm_scale(const float* __restrict__ h,
                                                    const float* __restrict__ W,
                                                    const float* __restrict__ dis,
                                                    float* __restrict__ tmp, int n) {
  __shared__ float Ws[128 * 128];   // 64 KB
  __shared__ float hs[128 * 32];    // 16 KB
  const int tid = threadIdx.x;

  for (int i = tid * 4; i < 128 * 128; i += 256 * 4)
    *reinterpret_cast<float4*>(&Ws[i]) = *reinterpret_cast<const float4*>(&W[i]);

  const int row0 = blockIdx.x * 32;
  for (int i = tid; i < 32 * 128; i += 256) {
    int r = i >> 7, c = i & 127;   // 64 lanes share r, c consecutive -> swizzle
    int gr = row0 + r;
    float v = (gr < n) ? h[(size_t)gr * 128 + c] : 0.0f;
    hs[(c << 5) + (r ^ ((c & 7) << 2))] = v;
  }
  __syncthreads();

  const int r0 = (tid >> 5) << 2;  // 8 row groups of 4 rows
  const int j0 = (tid & 31) << 2;  // 32 col groups of 4 cols
  float4 a0 = {0, 0, 0, 0}, a1 = {0, 0, 0, 0}, a2 = {0, 0, 0, 0}, a3 = {0, 0, 0, 0};

#pragma unroll 8
  for (int k = 0; k < 128; ++k) {
    // floats at (k,r0^s .. +3) map back to rows r0..r0+3 in order
    float4 hv = *reinterpret_cast<const float4*>(&hs[(k << 5) + (r0 ^ ((k & 7) << 2))]);
    float4 wv = *reinterpret_cast<const float4*>(&Ws[(k << 7) + j0]);
    a0.x = fmaf(hv.x, wv.x, a0.x); a0.y = fmaf(hv.x, wv.y, a0.y);
    a0.z = fmaf(hv.x, wv.z, a0.z); a0.w = fmaf(hv.x, wv.w, a0.w);
    a1.x = fmaf(hv.y, wv.x, a1.x); a1.y = fmaf(hv.y, wv.y, a1.y);
    a1.z = fmaf(hv.y, wv.z, a1.z); a1.w = fmaf(hv.y, wv.w, a1.w);
    a2.x = fmaf(hv.z, wv.x, a2.x); a2.y = fmaf(hv.z, wv.y, a2.y);
    a2.z = fmaf(hv.z, wv.z, a2.z); a2.w = fmaf(hv.z, wv.w, a2.w);
    a3.x = fmaf(hv.w, wv.x, a3.x); a3.y = fmaf(hv.w, wv.y, a3.y);
    a3.z = fmaf(hv.w, wv.z, a3.z); a3.w = fmaf(hv.w, wv.w, a3.w);
  }

#pragma unroll
  for (int m = 0; m < 4; ++m) {
    int gr = row0 + r0 + m;
    if (gr < n) {
      float dn = dis[gr];
      float4 a = (m == 0) ? a0 : (m == 1) ? a1 : (m == 2) ? a2 : a3;
      a.x *= dn; a.y *= dn; a.z *= dn; a.w *= dn;
      *reinterpret_cast<float4*>(&tmp[(size_t)gr * 128 + j0]) = a;
    }
  }
}

// h_out[d,:] = relu(dis[d] * (sum_{src in-edges} tmp[src,:] + tmp[d,:]) + b)
// one 64-lane wave per node, float2 per lane, 4 edge rows in flight.
__global__ __launch_bounds__(256) void k_gather(const float* __restrict__ tmp,
                                                const int* __restrict__ csr,
                                                const int* __restrict__ offs,
                                                const float* __restrict__ dis,
                                                const float* __restrict__ bias,
                                                float* __restrict__ hout, int n) {
  int node = blockIdx.x * 4 + (threadIdx.x >> 6);
  if (node >= n) return;
  int lane = threadIdx.x & 63;
  int c = lane * 2;
  int s0 = offs[node], s1 = offs[node + 1];

  float ax = 0.f, ay = 0.f, bx = 0.f, by = 0.f;
  float cx = 0.f, cy = 0.f, dx = 0.f, dy = 0.f;
  int e = s0;
  for (; e + 3 < s1; e += 4) {
    int sA = csr[e], sB = csr[e + 1], sC = csr[e + 2], sD = csr[e + 3];
    float2 vA = *reinterpret_cast<const float2*>(&tmp[(size_t)sA * 128 + c]);
    float2 vB = *reinterpret_cast<const float2*>(&tmp[(size_t)sB * 128 + c]);
    float2 vC = *reinterpret_cast<const float2*>(&tmp[(size_t)sC * 128 + c]);
    float2 vD = *reinterpret_cast<const float2*>(&tmp[(size_t)sD * 128 + c]);
    ax += vA.x; ay += vA.y; bx += vB.x; by += vB.y;
    cx += vC.x; cy += vC.y; dx += vD.x; dy += vD.y;
  }
  for (; e < s1; ++e) {
    int sA = csr[e];
    float2 vA = *reinterpret_cast<const float2*>(&tmp[(size_t)sA * 128 + c]);
    ax += vA.x; ay += vA.y;
  }
  float2 sv = *reinterpret_cast<const float2*>(&tmp[(size_t)node * 128 + c]);
  ax += bx + cx + dx + sv.x;
  ay += by + cy + dy + sv.y;

  float dn = dis[node];
  float2 bb = *reinterpret_cast<const float2*>(&bias[c]);
  float rx = fmaf(dn, ax, bb.x);
  float ry = fmaf(dn, ay, bb.y);
  rx = rx > 0.f ? rx : 0.f;
  ry = ry > 0.f ? ry : 0.f;
  float2 res; res.x = rx; res.y = ry;
  *reinterpret_cast<float2*>(&hout[(size_t)node * 128 + c]) = res;
}

// column sums of h -> pooled[128] (block-local reduce, 128 atomics/block)
__global__ __launch_bounds__(256) void k_pool(const float* __restrict__ h,
                                              float* __restrict__ pooled, int n) {
  int col = threadIdx.x & 127;
  int half = threadIdx.x >> 7;
  float acc = 0.f;
  for (int r = blockIdx.x * 2 + half; r < n; r += gridDim.x * 2)
    acc += h[(size_t)r * 128 + col];
  __shared__ float red[256];
  red[threadIdx.x] = acc;
  __syncthreads();
  if (threadIdx.x < 128)
    atomicAdd(&pooled[threadIdx.x], red[threadIdx.x] + red[threadIdx.x + 128]);
}

__global__ void k_final(const float* __restrict__ pooled, const float* __restrict__ Wfc,
                        const float* __restrict__ bfc, float* __restrict__ out,
                        float invn) {
  int j = threadIdx.x;
  if (j < 32) {
    float acc = 0.f;
    for (int k = 0; k < 128; ++k) acc = fmaf(pooled[k], Wfc[k * 32 + j], acc);
    out[j] = fmaf(acc, invn, bfc[j]);
  }
}

extern "C" void kernel_launch(void* const* d_in, const int* in_sizes, int n_in,
                              void* d_out, int out_size, void* d_ws, size_t ws_size,
                              hipStream_t stream) {
  const float* x   = (const float*)d_in[0];
  const int*   ei  = (const int*)d_in[1];
  const float* W0  = (const float*)d_in[2];
  const float* b0  = (const float*)d_in[3];
  const float* W1  = (const float*)d_in[4];
  const float* b1  = (const float*)d_in[5];
  const float* W2  = (const float*)d_in[6];
  const float* b2  = (const float*)d_in[7];
  const float* Wfc = (const float*)d_in[8];
  const float* bfc = (const float*)d_in[9];

  const int n = in_sizes[0] / 128;
  const int e = in_sizes[1] / 2;

  char* ws = (char*)d_ws;
  size_t off = 0;
  auto alloc = [&](size_t bytes) -> void* {
    void* p = ws + off;
    off = (off + bytes + 255) & ~(size_t)255;
    return p;
  };
  int*   mode   = (int*)alloc(sizeof(int));
  int*   count  = (int*)alloc((size_t)n * 4);
  int*   offs   = (int*)alloc((size_t)(n + 1) * 4);
  int*   cursor = (int*)alloc((size_t)n * 4);
  float* dis    = (float*)alloc((size_t)n * 4);
  int*   csr    = (int*)alloc((size_t)e * 4);
  float* pooled = (float*)alloc(128 * 4);
  int*   bsum   = (int*)alloc(((size_t)(n + 1023) / 1024) * 4);
  float* bufA   = (float*)alloc((size_t)n * 128 * 4);
  float* bufB   = (float*)alloc((size_t)n * 128 * 4);

  int gz = (n + 255) / 256;
  int ge = (e + 255) / 256;
  int nb = (n + 1023) / 1024;

  k_detect<<<1, 256, 0, stream>>>(ei, mode, e);
  k_zero<<<gz, 256, 0, stream>>>(count, pooled, n);
  k_hist<<<ge, 256, 0, stream>>>(ei, mode, count, e);
  k_scan1<<<nb, 256, 0, stream>>>(count, bsum, n);
  k_scan2<<<1, 1024, 0, stream>>>(bsum, nb);
  k_scan3<<<nb, 256, 0, stream>>>(count, bsum, offs, cursor, dis, n, e);
  k_fill<<<ge, 256, 0, stream>>>(ei, mode, cursor, csr, e);

  const float* Ws_[3] = {W0, W1, W2};
  const float* bs_[3] = {b0, b1, b2};
  const float* hin = x;
  int gg = (n + 31) / 32;
  int gn = (n + 3) / 4;
  for (int l = 0; l < 3; ++l) {
    k_gemm_scale<<<gg, 256, 0, stream>>>(hin, Ws_[l], dis, bufB, n);
    k_gather<<<gn, 256, 0, stream>>>(bufB, csr, offs, dis, bs_[l], bufA, n);
    hin = bufA;
  }

  k_pool<<<256, 256, 0, stream>>>(bufA, pooled, n);
  k_final<<<1, 32, 0, stream>>>(pooled, Wfc, bfc, (float*)d_out, 1.0f / (float)n);
}

// Round 3
// 666.980 us; speedup vs baseline: 1.9440x; 1.3219x over previous
//
#include <hip/hip_runtime.h>
#include <hip/hip_bf16.h>
#include <cstdint>

// ---------------------------------------------------------------------------
// GCN 3-layer forward: h = relu(Â (h W) + b) x3, mean-pool, final linear.
// R3: CSR build via 2-level radix-by-dst (LDS-staged, coalesced writes)
//     replacing atomic-scatter fill (was 105MB write-amplified, 133us).
//     Persistent GEMM: W staged once per block, register-prefetched h tiles.
// ---------------------------------------------------------------------------

#define NBMAX 256   // max coarse buckets (n <= 131072 with BKSH=9)
#define BKSH  9     // 512 dst nodes per bucket
#define SCH   2048  // edges per scatter chunk

// Detect whether edge_index arrived as int64 (odd int32 words all zero) or
// int32. Writes mode[0] = 1 for int64, 0 for int32.
__global__ void k_detect(const int* __restrict__ ei, int* __restrict__ mode, int e) {
  __shared__ int any;
  if (threadIdx.x == 0) any = 0;
  __syncthreads();
  int lim = min(e, 2048);
  int local = 0;
  for (int i = threadIdx.x; i < lim; i += blockDim.x)
    local |= (ei[2 * i + 1] != 0);
  if (local) atomicOr(&any, 1);
  __syncthreads();
  if (threadIdx.x == 0) mode[0] = (any == 0) ? 1 : 0;
}

__global__ void k_zero(int* __restrict__ bucketCnt, float* __restrict__ pooled, int nb) {
  int i = threadIdx.x;
  if (i < nb) bucketCnt[i] = 0;
  if (i < 128) pooled[i] = 0.0f;
}

// coarse bucket histogram via LDS
__global__ __launch_bounds__(256) void b_count(const int* __restrict__ ei,
                                               const int* __restrict__ mode,
                                               int* __restrict__ bucketCnt,
                                               int e, int nb) {
  __shared__ int lh[NBMAX];
  int t = threadIdx.x;
  lh[t] = 0;
  __syncthreads();
  int m = mode[0];
  int stride = gridDim.x * 256;
  for (int i = blockIdx.x * 256 + t; i < e; i += stride) {
    long long di = (long long)e + i;
    int d = m ? ei[2 * di] : ei[di];
    atomicAdd(&lh[d >> BKSH], 1);
  }
  __syncthreads();
  if (t < nb && lh[t]) atomicAdd(&bucketCnt[t], lh[t]);
}

// exclusive scan of bucket counts (single block)
__global__ __launch_bounds__(256) void b_bscan(const int* __restrict__ bucketCnt,
                                               int* __restrict__ bucketOff,
                                               int* __restrict__ bucketCur,
                                               int nb, int e) {
  __shared__ int sh[NBMAX];
  int t = threadIdx.x;
  int c = (t < nb) ? bucketCnt[t] : 0;
  sh[t] = c;
  __syncthreads();
  for (int d = 1; d < NBMAX; d <<= 1) {
    int v = (t >= d) ? sh[t - d] : 0;
    __syncthreads();
    sh[t] += v;
    __syncthreads();
  }
  int ex = sh[t] - c;
  if (t < nb) { bucketOff[t] = ex; bucketCur[t] = ex; }
  if (t == 0) bucketOff[nb] = e;
}

// LDS-staged scatter of (src,dst) pairs into coarse bucket regions.
// Per-bucket chunks written contiguously (~84B) -> little write amplification.
__global__ __launch_bounds__(256) void b_scatter(const int* __restrict__ ei,
                                                 const int* __restrict__ mode,
                                                 int* __restrict__ bucketCur,
                                                 int* __restrict__ pairBuf,
                                                 int e, int nb) {
  __shared__ int cnt[NBMAX];   // counts, then exclusive prefix
  __shared__ int pre[NBMAX];   // inclusive prefix
  __shared__ int base[NBMAX];  // global base for this block's chunk
  __shared__ int stage[2 * SCH];
  const int t = threadIdx.x;
  const int chunk0 = blockIdx.x * SCH;
  const int nloc = min(SCH, e - chunk0);
  const int m = mode[0];

  cnt[t] = 0;
  __syncthreads();

  int myS[SCH / 256], myD[SCH / 256], myB[SCH / 256], mySlot[SCH / 256];
#pragma unroll
  for (int j = 0; j < SCH / 256; ++j) {
    int li = j * 256 + t;
    myB[j] = -1;
    if (li < nloc) {
      int i = chunk0 + li;
      long long di = (long long)e + i;
      int s = m ? ei[2 * (long long)i] : ei[i];
      int d = m ? ei[2 * di] : ei[di];
      int b = d >> BKSH;
      myS[j] = s; myD[j] = d; myB[j] = b;
      mySlot[j] = atomicAdd(&cnt[b], 1);
    }
  }
  __syncthreads();

  int c0 = cnt[t];
  pre[t] = c0;
  __syncthreads();
  for (int d = 1; d < NBMAX; d <<= 1) {
    int v = (t >= d) ? pre[t - d] : 0;
    __syncthreads();
    pre[t] += v;
    __syncthreads();
  }
  int myPre = pre[t] - c0;  // exclusive
  if (t < nb && c0 > 0) base[t] = atomicAdd(&bucketCur[t], c0);
  __syncthreads();
  cnt[t] = myPre;           // cnt[] now = exclusive prefix
  __syncthreads();

#pragma unroll
  for (int j = 0; j < SCH / 256; ++j) {
    if (myB[j] >= 0) {
      int si = cnt[myB[j]] + mySlot[j];
      stage[2 * si] = myS[j];
      stage[2 * si + 1] = myD[j];
    }
  }
  __syncthreads();

  // flush: one wave per bucket (cyclic), lanes copy the contiguous run
  int wave = t >> 6, lane = t & 63;
  for (int b = wave; b < nb; b += 4) {
    int cb = pre[b] - cnt[b];  // inclusive - exclusive = count
    if (cb <= 0) continue;
    int lo = cnt[b];
    size_t gb = (size_t)base[b];
    for (int j = lane; j < 2 * cb; j += 64)
      pairBuf[2 * gb + j] = stage[2 * lo + j];
  }
}

// per-bucket fine CSR: counts, offs, dis, csr — all within an L2-resident
// 32KB csr region per bucket, so scatter writes coalesce in L2.
__global__ __launch_bounds__(512) void b_fine(const int* __restrict__ pairBuf,
                                              const int* __restrict__ bucketOff,
                                              int* __restrict__ offs,
                                              float* __restrict__ dis,
                                              int* __restrict__ csr,
                                              int n, int e) {
  const int b = blockIdx.x;
  const int d0 = b << BKSH;
  const int lo = bucketOff[b], hi = bucketOff[b + 1];
  __shared__ int arr[1 << BKSH];
  __shared__ int cur[1 << BKSH];
  const int t = threadIdx.x;
  arr[t] = 0; cur[t] = 0;
  __syncthreads();
  for (int i = lo + t; i < hi; i += 512) {
    int d = pairBuf[2 * (size_t)i + 1];
    atomicAdd(&arr[d - d0], 1);
  }
  __syncthreads();
  int c0 = arr[t];
  __syncthreads();
  for (int dd = 1; dd < 512; dd <<= 1) {  // inclusive scan
    int v = (t >= dd) ? arr[t - dd] : 0;
    __syncthreads();
    arr[t] += v;
    __syncthreads();
  }
  int epre = arr[t] - c0;
  int gd = d0 + t;
  if (gd < n) {
    offs[gd] = lo + epre;
    dis[gd] = rsqrtf((float)c0 + 1.0f);
  }
  __syncthreads();
  arr[t] = epre;  // arr[] now = exclusive prefix
  __syncthreads();
  for (int i = lo + t; i < hi; i += 512) {
    int s = pairBuf[2 * (size_t)i];
    int d = pairBuf[2 * (size_t)i + 1];
    int ld = d - d0;
    int p = lo + arr[ld] + atomicAdd(&cur[ld], 1);
    csr[p] = s;
  }
  if (b == 0 && t == 0) offs[n] = e;
}

// tmp[r,:] = dis[r] * (h[r,:] @ W)
// Persistent: W (64KB) staged once per block; each block loops over row tiles
// with register prefetch of the next tile overlapping the k-loop.
__global__ __launch_bounds__(256) void k_gemm_scale(const float* __restrict__ h,
                                                    const float* __restrict__ W,
                                                    const float* __restrict__ dis,
                                                    float* __restrict__ tmp,
                                                    int n, int ntiles) {
  __shared__ float Ws[128 * 128];  // 64 KB
  __shared__ float hs[128 * 32];   // 16 KB, transposed [k][32] + XOR swizzle
  const int tid = threadIdx.x;

  for (int i = tid * 4; i < 128 * 128; i += 256 * 4)
    *reinterpret_cast<float4*>(&Ws[i]) = *reinterpret_cast<const float4*>(&W[i]);

  const int sr = tid >> 3;         // staging row 0..31
  const int sc = (tid & 7) << 4;   // staging col base
  const int r0 = (tid >> 5) << 2;  // compute: 4-row group
  const int j0 = (tid & 31) << 2;  // compute: 4-col group

  float4 p[4];
  int t = blockIdx.x;
  {
    bool ok = (t < ntiles) && (t * 32 + sr < n);
    const float* src = &h[(size_t)(t * 32 + sr) * 128 + sc];
#pragma unroll
    for (int q = 0; q < 4; ++q)
      p[q] = ok ? *reinterpret_cast<const float4*>(src + q * 4) : float4{0, 0, 0, 0};
  }

  for (; t < ntiles; t += gridDim.x) {
    __syncthreads();  // hs consumers from previous tile done
#pragma unroll
    for (int q = 0; q < 4; ++q) {
      float vq[4] = {p[q].x, p[q].y, p[q].z, p[q].w};
#pragma unroll
      for (int u = 0; u < 4; ++u) {
        int c = sc + q * 4 + u;
        hs[(c << 5) + (sr ^ ((c & 7) << 2))] = vq[u];
      }
    }
    __syncthreads();

    int tn = t + gridDim.x;  // prefetch next tile into regs
    {
      bool ok = (tn < ntiles) && (tn * 32 + sr < n);
      const float* src = &h[(size_t)(tn * 32 + sr) * 128 + sc];
#pragma unroll
      for (int q = 0; q < 4; ++q)
        p[q] = ok ? *reinterpret_cast<const float4*>(src + q * 4) : float4{0, 0, 0, 0};
    }

    float4 a0 = {0, 0, 0, 0}, a1 = {0, 0, 0, 0}, a2 = {0, 0, 0, 0}, a3 = {0, 0, 0, 0};
#pragma unroll 8
    for (int k = 0; k < 128; ++k) {
      float4 hv = *reinterpret_cast<const float4*>(&hs[(k << 5) + (r0 ^ ((k & 7) << 2))]);
      float4 wv = *reinterpret_cast<const float4*>(&Ws[(k << 7) + j0]);
      a0.x = fmaf(hv.x, wv.x, a0.x); a0.y = fmaf(hv.x, wv.y, a0.y);
      a0.z = fmaf(hv.x, wv.z, a0.z); a0.w = fmaf(hv.x, wv.w, a0.w);
      a1.x = fmaf(hv.y, wv.x, a1.x); a1.y = fmaf(hv.y, wv.y, a1.y);
      a1.z = fmaf(hv.y, wv.z, a1.z); a1.w = fmaf(hv.y, wv.w, a1.w);
      a2.x = fmaf(hv.z, wv.x, a2.x); a2.y = fmaf(hv.z, wv.y, a2.y);
      a2.z = fmaf(hv.z, wv.z, a2.z); a2.w = fmaf(hv.z, wv.w, a2.w);
      a3.x = fmaf(hv.w, wv.x, a3.x); a3.y = fmaf(hv.w, wv.y, a3.y);
      a3.z = fmaf(hv.w, wv.z, a3.z); a3.w = fmaf(hv.w, wv.w, a3.w);
    }

    int row0 = t * 32;
#pragma unroll
    for (int mm = 0; mm < 4; ++mm) {
      int gr = row0 + r0 + mm;
      if (gr < n) {
        float dn = dis[gr];
        float4 a = (mm == 0) ? a0 : (mm == 1) ? a1 : (mm == 2) ? a2 : a3;
        a.x *= dn; a.y *= dn; a.z *= dn; a.w *= dn;
        *reinterpret_cast<float4*>(&tmp[(size_t)gr * 128 + j0]) = a;
      }
    }
  }
}

// h_out[d,:] = relu(dis[d] * (sum_{src in-edges} tmp[src,:] + tmp[d,:]) + b)
__global__ __launch_bounds__(256) void k_gather(const float* __restrict__ tmp,
                                                const int* __restrict__ csr,
                                                const int* __restrict__ offs,
                                                const float* __restrict__ dis,
                                                const float* __restrict__ bias,
                                                float* __restrict__ hout, int n) {
  int node = blockIdx.x * 4 + (threadIdx.x >> 6);
  if (node >= n) return;
  int lane = threadIdx.x & 63;
  int c = lane * 2;
  int s0 = offs[node], s1 = offs[node + 1];

  float ax = 0.f, ay = 0.f, bx = 0.f, by = 0.f;
  float cx = 0.f, cy = 0.f, dx = 0.f, dy = 0.f;
  int e = s0;
  for (; e + 3 < s1; e += 4) {
    int sA = csr[e], sB = csr[e + 1], sC = csr[e + 2], sD = csr[e + 3];
    float2 vA = *reinterpret_cast<const float2*>(&tmp[(size_t)sA * 128 + c]);
    float2 vB = *reinterpret_cast<const float2*>(&tmp[(size_t)sB * 128 + c]);
    float2 vC = *reinterpret_cast<const float2*>(&tmp[(size_t)sC * 128 + c]);
    float2 vD = *reinterpret_cast<const float2*>(&tmp[(size_t)sD * 128 + c]);
    ax += vA.x; ay += vA.y; bx += vB.x; by += vB.y;
    cx += vC.x; cy += vC.y; dx += vD.x; dy += vD.y;
  }
  for (; e < s1; ++e) {
    int sA = csr[e];
    float2 vA = *reinterpret_cast<const float2*>(&tmp[(size_t)sA * 128 + c]);
    ax += vA.x; ay += vA.y;
  }
  float2 sv = *reinterpret_cast<const float2*>(&tmp[(size_t)node * 128 + c]);
  ax += bx + cx + dx + sv.x;
  ay += by + cy + dy + sv.y;

  float dn = dis[node];
  float2 bb = *reinterpret_cast<const float2*>(&bias[c]);
  float rx = fmaf(dn, ax, bb.x);
  float ry = fmaf(dn, ay, bb.y);
  rx = rx > 0.f ? rx : 0.f;
  ry = ry > 0.f ? ry : 0.f;
  float2 res; res.x = rx; res.y = ry;
  *reinterpret_cast<float2*>(&hout[(size_t)node * 128 + c]) = res;
}

__global__ __launch_bounds__(256) void k_pool(const float* __restrict__ h,
                                              float* __restrict__ pooled, int n) {
  int col = threadIdx.x & 127;
  int half = threadIdx.x >> 7;
  float acc = 0.f;
  for (int r = blockIdx.x * 2 + half; r < n; r += gridDim.x * 2)
    acc += h[(size_t)r * 128 + col];
  __shared__ float red[256];
  red[threadIdx.x] = acc;
  __syncthreads();
  if (threadIdx.x < 128)
    atomicAdd(&pooled[threadIdx.x], red[threadIdx.x] + red[threadIdx.x + 128]);
}

__global__ void k_final(const float* __restrict__ pooled, const float* __restrict__ Wfc,
                        const float* __restrict__ bfc, float* __restrict__ out,
                        float invn) {
  int j = threadIdx.x;
  if (j < 32) {
    float acc = 0.f;
    for (int k = 0; k < 128; ++k) acc = fmaf(pooled[k], Wfc[k * 32 + j], acc);
    out[j] = fmaf(acc, invn, bfc[j]);
  }
}

extern "C" void kernel_launch(void* const* d_in, const int* in_sizes, int n_in,
                              void* d_out, int out_size, void* d_ws, size_t ws_size,
                              hipStream_t stream) {
  const float* x   = (const float*)d_in[0];
  const int*   ei  = (const int*)d_in[1];
  const float* W0  = (const float*)d_in[2];
  const float* b0  = (const float*)d_in[3];
  const float* W1  = (const float*)d_in[4];
  const float* b1  = (const float*)d_in[5];
  const float* W2  = (const float*)d_in[6];
  const float* b2  = (const float*)d_in[7];
  const float* Wfc = (const float*)d_in[8];
  const float* bfc = (const float*)d_in[9];

  const int n = in_sizes[0] / 128;
  const int e = in_sizes[1] / 2;
  const int nb = (n + (1 << BKSH) - 1) >> BKSH;  // 196 for n=100000 (<=NBMAX)

  char* ws = (char*)d_ws;
  size_t off = 0;
  auto alloc = [&](size_t bytes) -> void* {
    void* p = ws + off;
    off = (off + bytes + 255) & ~(size_t)255;
    return p;
  };
  int*   mode      = (int*)alloc(sizeof(int));
  int*   bucketCnt = (int*)alloc(NBMAX * 4);
  int*   bucketOff = (int*)alloc((NBMAX + 1) * 4);
  int*   bucketCur = (int*)alloc(NBMAX * 4);
  int*   offs      = (int*)alloc((size_t)(n + 1) * 4);
  float* dis       = (float*)alloc((size_t)n * 4);
  int*   csr       = (int*)alloc((size_t)e * 4);
  float* pooled    = (float*)alloc(128 * 4);
  float* bufA      = (float*)alloc((size_t)n * 128 * 4);
  float* bufB      = (float*)alloc((size_t)n * 128 * 4);
  int*   pairBuf   = (int*)bufB;  // alias: pairs only needed before first GEMM

  k_detect<<<1, 256, 0, stream>>>(ei, mode, e);
  k_zero<<<1, 256, 0, stream>>>(bucketCnt, pooled, nb);
  b_count<<<192, 256, 0, stream>>>(ei, mode, bucketCnt, e, nb);
  b_bscan<<<1, 256, 0, stream>>>(bucketCnt, bucketOff, bucketCur, nb, e);
  b_scatter<<<(e + SCH - 1) / SCH, 256, 0, stream>>>(ei, mode, bucketCur, pairBuf, e, nb);
  b_fine<<<nb, 512, 0, stream>>>(pairBuf, bucketOff, offs, dis, csr, n, e);

  const float* Ws_[3] = {W0, W1, W2};
  const float* bs_[3] = {b0, b1, b2};
  const float* hin = x;
  int ntiles = (n + 31) / 32;
  int gg = min(512, ntiles);
  int gn = (n + 3) / 4;
  for (int l = 0; l < 3; ++l) {
    k_gemm_scale<<<gg, 256, 0, stream>>>(hin, Ws_[l], dis, bufB, n, ntiles);
    k_gather<<<gn, 256, 0, stream>>>(bufB, csr, offs, dis, bs_[l], bufA, n);
    hin = bufA;
  }

  k_pool<<<256, 256, 0, stream>>>(bufA, pooled, n);
  k_final<<<1, 32, 0, stream>>>(pooled, Wfc, bfc, (float*)d_out, 1.0f / (float)n);
}

// Round 4
// 418.675 us; speedup vs baseline: 3.0969x; 1.5931x over previous
//
#include <hip/hip_runtime.h>
#include <hip/hip_bf16.h>
#include <cstdint>

// ---------------------------------------------------------------------------
// GCN 3-layer forward, bf16 feature pipeline + MFMA GEMM.
// R4: tmp/h stored bf16 (fp32 accum) -> gather bytes halved;
//     GEMM via mfma_f32_16x16x32_bf16 with k-permutation-safe packing
//     (A and B share per-lane k-order => correct for any native k layout).
// ---------------------------------------------------------------------------

typedef unsigned short u16;
typedef unsigned int u32;
typedef __attribute__((ext_vector_type(8))) short short8v;
typedef __attribute__((ext_vector_type(4))) float f32x4;

#define NBMAX 256
#define BKSH  9
#define SCH   2048

__device__ inline u16 f2bf(float f) {
  u32 u = __float_as_uint(f);
  u += 0x7fff + ((u >> 16) & 1);  // RNE
  return (u16)(u >> 16);
}
__device__ inline float bflo(u32 u) { return __uint_as_float(u << 16); }
__device__ inline float bfhi(u32 u) { return __uint_as_float(u & 0xffff0000u); }

// --- edge-index dtype detect ------------------------------------------------
__global__ void k_detect(const int* __restrict__ ei, int* __restrict__ mode, int e) {
  __shared__ int any;
  if (threadIdx.x == 0) any = 0;
  __syncthreads();
  int lim = min(e, 2048);
  int local = 0;
  for (int i = threadIdx.x; i < lim; i += blockDim.x)
    local |= (ei[2 * i + 1] != 0);
  if (local) atomicOr(&any, 1);
  __syncthreads();
  if (threadIdx.x == 0) mode[0] = (any == 0) ? 1 : 0;
}

__global__ void k_zero(int* __restrict__ bucketCnt, float* __restrict__ pooled, int nb) {
  int i = threadIdx.x;
  if (i < nb) bucketCnt[i] = 0;
  if (i < 128) pooled[i] = 0.0f;
}

// --- CSR build: 2-level radix by destination --------------------------------
__global__ __launch_bounds__(256) void b_count(const int* __restrict__ ei,
                                               const int* __restrict__ mode,
                                               int* __restrict__ bucketCnt,
                                               int e, int nb) {
  __shared__ int lh[NBMAX];
  int t = threadIdx.x;
  lh[t] = 0;
  __syncthreads();
  int m = mode[0];
  int stride = gridDim.x * 256;
  for (int i = blockIdx.x * 256 + t; i < e; i += stride) {
    long long di = (long long)e + i;
    int d = m ? ei[2 * di] : ei[di];
    atomicAdd(&lh[d >> BKSH], 1);
  }
  __syncthreads();
  if (t < nb && lh[t]) atomicAdd(&bucketCnt[t], lh[t]);
}

__global__ __launch_bounds__(256) void b_bscan(const int* __restrict__ bucketCnt,
                                               int* __restrict__ bucketOff,
                                               int* __restrict__ bucketCur,
                                               int nb, int e) {
  __shared__ int sh[NBMAX];
  int t = threadIdx.x;
  int c = (t < nb) ? bucketCnt[t] : 0;
  sh[t] = c;
  __syncthreads();
  for (int d = 1; d < NBMAX; d <<= 1) {
    int v = (t >= d) ? sh[t - d] : 0;
    __syncthreads();
    sh[t] += v;
    __syncthreads();
  }
  int ex = sh[t] - c;
  if (t < nb) { bucketOff[t] = ex; bucketCur[t] = ex; }
  if (t == 0) bucketOff[nb] = e;
}

__global__ __launch_bounds__(256) void b_scatter(const int* __restrict__ ei,
                                                 const int* __restrict__ mode,
                                                 int* __restrict__ bucketCur,
                                                 int* __restrict__ pairBuf,
                                                 int e, int nb) {
  __shared__ int cnt[NBMAX];
  __shared__ int pre[NBMAX];
  __shared__ int base[NBMAX];
  __shared__ int stage[2 * SCH];
  const int t = threadIdx.x;
  const int chunk0 = blockIdx.x * SCH;
  const int nloc = min(SCH, e - chunk0);
  const int m = mode[0];

  cnt[t] = 0;
  __syncthreads();

  int myS[SCH / 256], myD[SCH / 256], myB[SCH / 256], mySlot[SCH / 256];
#pragma unroll
  for (int j = 0; j < SCH / 256; ++j) {
    int li = j * 256 + t;
    myB[j] = -1;
    if (li < nloc) {
      int i = chunk0 + li;
      long long di = (long long)e + i;
      int s = m ? ei[2 * (long long)i] : ei[i];
      int d = m ? ei[2 * di] : ei[di];
      int b = d >> BKSH;
      myS[j] = s; myD[j] = d; myB[j] = b;
      mySlot[j] = atomicAdd(&cnt[b], 1);
    }
  }
  __syncthreads();

  int c0 = cnt[t];
  pre[t] = c0;
  __syncthreads();
  for (int d = 1; d < NBMAX; d <<= 1) {
    int v = (t >= d) ? pre[t - d] : 0;
    __syncthreads();
    pre[t] += v;
    __syncthreads();
  }
  int myPre = pre[t] - c0;
  if (t < nb && c0 > 0) base[t] = atomicAdd(&bucketCur[t], c0);
  __syncthreads();
  cnt[t] = myPre;
  __syncthreads();

#pragma unroll
  for (int j = 0; j < SCH / 256; ++j) {
    if (myB[j] >= 0) {
      int si = cnt[myB[j]] + mySlot[j];
      stage[2 * si] = myS[j];
      stage[2 * si + 1] = myD[j];
    }
  }
  __syncthreads();

  int wave = t >> 6, lane = t & 63;
  for (int b = wave; b < nb; b += 4) {
    int cb = pre[b] - cnt[b];
    if (cb <= 0) continue;
    int lo = cnt[b];
    size_t gb = (size_t)base[b];
    for (int j = lane; j < 2 * cb; j += 64)
      pairBuf[2 * gb + j] = stage[2 * lo + j];
  }
}

__global__ __launch_bounds__(512) void b_fine(const int* __restrict__ pairBuf,
                                              const int* __restrict__ bucketOff,
                                              int* __restrict__ offs,
                                              float* __restrict__ dis,
                                              int* __restrict__ csr,
                                              int n, int e) {
  const int b = blockIdx.x;
  const int d0 = b << BKSH;
  const int lo = bucketOff[b], hi = bucketOff[b + 1];
  __shared__ int arr[1 << BKSH];
  __shared__ int cur[1 << BKSH];
  const int t = threadIdx.x;
  arr[t] = 0; cur[t] = 0;
  __syncthreads();
  for (int i = lo + t; i < hi; i += 512) {
    int d = pairBuf[2 * (size_t)i + 1];
    atomicAdd(&arr[d - d0], 1);
  }
  __syncthreads();
  int c0 = arr[t];
  __syncthreads();
  for (int dd = 1; dd < 512; dd <<= 1) {
    int v = (t >= dd) ? arr[t - dd] : 0;
    __syncthreads();
    arr[t] += v;
    __syncthreads();
  }
  int epre = arr[t] - c0;
  int gd = d0 + t;
  if (gd < n) {
    offs[gd] = lo + epre;
    dis[gd] = rsqrtf((float)c0 + 1.0f);
  }
  __syncthreads();
  arr[t] = epre;
  __syncthreads();
  for (int i = lo + t; i < hi; i += 512) {
    int s = pairBuf[2 * (size_t)i];
    int d = pairBuf[2 * (size_t)i + 1];
    int ld = d - d0;
    int p = lo + arr[ld] + atomicAdd(&cur[ld], 1);
    csr[p] = s;
  }
  if (b == 0 && t == 0) offs[n] = e;
}

// --- x fp32 -> bf16 ---------------------------------------------------------
__global__ __launch_bounds__(256) void k_xcvt(const float* __restrict__ x,
                                              u16* __restrict__ xb, size_t total4) {
  size_t i = (size_t)blockIdx.x * 256 + threadIdx.x;
  size_t stride = (size_t)gridDim.x * 256;
  for (; i < total4; i += stride) {
    float4 v = *reinterpret_cast<const float4*>(x + i * 4);
    u32 lo = (u32)f2bf(v.x) | ((u32)f2bf(v.y) << 16);
    u32 hi = (u32)f2bf(v.z) | ((u32)f2bf(v.w) << 16);
    uint2 o; o.x = lo; o.y = hi;
    *reinterpret_cast<uint2*>(xb + i * 4) = o;
  }
}

// --- pack W[128][128] fp32 -> MFMA B-fragments bf16 -------------------------
// frag f: ct = f>>8, kc = (f>>6)&3, lane = f&63; elem t = W[kc*32+8g+t][ct*16+c]
__global__ __launch_bounds__(256) void k_wpack(const float* __restrict__ W,
                                               u16* __restrict__ wp) {
  int f = blockIdx.x * 256 + threadIdx.x;
  if (f >= 2048) return;
  int ct = f >> 8, kc = (f >> 6) & 3, lane = f & 63;
  int g = lane >> 4, c = lane & 15;
  u32 o[4];
#pragma unroll
  for (int q = 0; q < 4; ++q) {
    int k = kc * 32 + g * 8 + q * 2;
    u16 e0 = f2bf(W[(size_t)k * 128 + ct * 16 + c]);
    u16 e1 = f2bf(W[(size_t)(k + 1) * 128 + ct * 16 + c]);
    o[q] = (u32)e0 | ((u32)e1 << 16);
  }
  uint4 v; v.x = o[0]; v.y = o[1]; v.z = o[2]; v.w = o[3];
  *reinterpret_cast<uint4*>(wp + (size_t)f * 8) = v;
}

// --- GEMM: tmp[r,:] = bf16( dis[r] * (h[r,:] @ W) ) via MFMA ----------------
// block = 256 thr = 4 waves, wave w -> rows [blk*64 + w*16, +16), all 128 cols.
// A-frag: lane l reads h[rowbase + (l&15)][k] k = kc*32 + 8*(l>>4) .. +7 (16B).
// B-frag: packed wpack, same per-lane k-order -> k-permutation cancels.
__global__ __launch_bounds__(256) void k_gemm_mfma(const u16* __restrict__ hb,
                                                   const u16* __restrict__ wp,
                                                   const float* __restrict__ dis,
                                                   u16* __restrict__ tmpb, int n) {
  __shared__ float eps[64 * 132];  // 33 KB, pitch 132 breaks bank aliasing
  const int tid = threadIdx.x;
  const int w = tid >> 6, l = tid & 63;
  const int g = l >> 4, c16 = l & 15;
  const int rowbase = blockIdx.x * 64 + w * 16;

  const short8v zero8 = {0, 0, 0, 0, 0, 0, 0, 0};
  short8v a[4];
  int ar = rowbase + c16;
  bool aok = ar < n;
  const u16* hrow = hb + (size_t)ar * 128;
#pragma unroll
  for (int kc = 0; kc < 4; ++kc)
    a[kc] = aok ? *reinterpret_cast<const short8v*>(hrow + kc * 32 + g * 8) : zero8;

  f32x4 acc[8];
#pragma unroll
  for (int ct = 0; ct < 8; ++ct) acc[ct] = f32x4{0.f, 0.f, 0.f, 0.f};

#pragma unroll
  for (int ct = 0; ct < 8; ++ct) {
#pragma unroll
    for (int kc = 0; kc < 4; ++kc) {
      short8v b = *reinterpret_cast<const short8v*>(wp + ((size_t)(ct * 4 + kc) * 64 + l) * 8);
      acc[ct] = __builtin_amdgcn_mfma_f32_16x16x32_bf16(a[kc], b, acc[ct], 0, 0, 0);
    }
  }

  // scale by dis[row] and stage fp32 to LDS (C/D: row = 4g+j, col = c16)
#pragma unroll
  for (int j = 0; j < 4; ++j) {
    int rl = w * 16 + g * 4 + j;
    int gr = blockIdx.x * 64 + rl;
    float dn = (gr < n) ? dis[gr] : 0.f;
#pragma unroll
    for (int ct = 0; ct < 8; ++ct)
      eps[rl * 132 + ct * 16 + c16] = acc[ct][j] * dn;
  }
  __syncthreads();

  // readback: thread -> (row rl, 32-col segment), emit coalesced bf16 stores
  int rl = tid >> 2, seg = tid & 3;
  int gr = blockIdx.x * 64 + rl;
  if (gr < n) {
    const float* src = &eps[rl * 132 + seg * 32];
#pragma unroll
    for (int q = 0; q < 4; ++q) {
      float4 v0 = *reinterpret_cast<const float4*>(src + q * 8);
      float4 v1 = *reinterpret_cast<const float4*>(src + q * 8 + 4);
      uint4 o;
      o.x = (u32)f2bf(v0.x) | ((u32)f2bf(v0.y) << 16);
      o.y = (u32)f2bf(v0.z) | ((u32)f2bf(v0.w) << 16);
      o.z = (u32)f2bf(v1.x) | ((u32)f2bf(v1.y) << 16);
      o.w = (u32)f2bf(v1.z) | ((u32)f2bf(v1.w) << 16);
      *reinterpret_cast<uint4*>(tmpb + (size_t)gr * 128 + seg * 32 + q * 8) = o;
    }
  }
}

// --- gather: hout[d,:] = bf16(relu(dis[d]*(sum_in tmp[src,:]+tmp[d,:]) + b))
// one wave per node, 1 uint (2 bf16) per lane, ILP x4, fp32 accumulation.
__global__ __launch_bounds__(256) void k_gather_bf(const u16* __restrict__ tmpb,
                                                   const int* __restrict__ csr,
                                                   const int* __restrict__ offs,
                                                   const float* __restrict__ dis,
                                                   const float* __restrict__ bias,
                                                   u16* __restrict__ houtb, int n) {
  int node = blockIdx.x * 4 + (threadIdx.x >> 6);
  if (node >= n) return;
  int lane = threadIdx.x & 63;
  const u32* tp = reinterpret_cast<const u32*>(tmpb);
  int s0 = offs[node], s1 = offs[node + 1];

  float ax = 0.f, ay = 0.f, bx = 0.f, by = 0.f;
  float cx = 0.f, cy = 0.f, dx = 0.f, dy = 0.f;
  int e = s0;
  for (; e + 3 < s1; e += 4) {
    u32 uA = tp[(size_t)csr[e] * 64 + lane];
    u32 uB = tp[(size_t)csr[e + 1] * 64 + lane];
    u32 uC = tp[(size_t)csr[e + 2] * 64 + lane];
    u32 uD = tp[(size_t)csr[e + 3] * 64 + lane];
    ax += bflo(uA); ay += bfhi(uA); bx += bflo(uB); by += bfhi(uB);
    cx += bflo(uC); cy += bfhi(uC); dx += bflo(uD); dy += bfhi(uD);
  }
  for (; e < s1; ++e) {
    u32 uA = tp[(size_t)csr[e] * 64 + lane];
    ax += bflo(uA); ay += bfhi(uA);
  }
  u32 uS = tp[(size_t)node * 64 + lane];
  float sx = ax + bx + cx + dx + bflo(uS);
  float sy = ay + by + cy + dy + bfhi(uS);

  float dn = dis[node];
  float2 bb = reinterpret_cast<const float2*>(bias)[lane];
  float rx = fmaf(dn, sx, bb.x);
  float ry = fmaf(dn, sy, bb.y);
  rx = rx > 0.f ? rx : 0.f;
  ry = ry > 0.f ? ry : 0.f;
  u32 o = (u32)f2bf(rx) | ((u32)f2bf(ry) << 16);
  reinterpret_cast<u32*>(houtb)[(size_t)node * 64 + lane] = o;
}

// --- mean-pool column sums (bf16 in, fp32 out) ------------------------------
__global__ __launch_bounds__(256) void k_pool_bf(const u16* __restrict__ h,
                                                 float* __restrict__ pooled, int n) {
  int lane = threadIdx.x & 63, wv = threadIdx.x >> 6;
  const u32* hp = reinterpret_cast<const u32*>(h);
  float sx = 0.f, sy = 0.f;
  for (int r = blockIdx.x * 4 + wv; r < n; r += gridDim.x * 4) {
    u32 u = hp[(size_t)r * 64 + lane];
    sx += bflo(u); sy += bfhi(u);
  }
  __shared__ float red[2][256];
  red[0][threadIdx.x] = sx;
  red[1][threadIdx.x] = sy;
  __syncthreads();
  if (threadIdx.x < 64) {
    float tx = red[0][threadIdx.x] + red[0][threadIdx.x + 64] +
               red[0][threadIdx.x + 128] + red[0][threadIdx.x + 192];
    float ty = red[1][threadIdx.x] + red[1][threadIdx.x + 64] +
               red[1][threadIdx.x + 128] + red[1][threadIdx.x + 192];
    atomicAdd(&pooled[threadIdx.x * 2], tx);
    atomicAdd(&pooled[threadIdx.x * 2 + 1], ty);
  }
}

__global__ void k_final(const float* __restrict__ pooled, const float* __restrict__ Wfc,
                        const float* __restrict__ bfc, float* __restrict__ out,
                        float invn) {
  int j = threadIdx.x;
  if (j < 32) {
    float acc = 0.f;
    for (int k = 0; k < 128; ++k) acc = fmaf(pooled[k], Wfc[k * 32 + j], acc);
    out[j] = fmaf(acc, invn, bfc[j]);
  }
}

extern "C" void kernel_launch(void* const* d_in, const int* in_sizes, int n_in,
                              void* d_out, int out_size, void* d_ws, size_t ws_size,
                              hipStream_t stream) {
  const float* x   = (const float*)d_in[0];
  const int*   ei  = (const int*)d_in[1];
  const float* W0  = (const float*)d_in[2];
  const float* b0  = (const float*)d_in[3];
  const float* W1  = (const float*)d_in[4];
  const float* b1  = (const float*)d_in[5];
  const float* W2  = (const float*)d_in[6];
  const float* b2  = (const float*)d_in[7];
  const float* Wfc = (const float*)d_in[8];
  const float* bfc = (const float*)d_in[9];

  const int n = in_sizes[0] / 128;
  const int e = in_sizes[1] / 2;
  const int nb = (n + (1 << BKSH) - 1) >> BKSH;

  char* ws = (char*)d_ws;
  size_t off = 0;
  auto alloc = [&](size_t bytes) -> void* {
    void* p = ws + off;
    off = (off + bytes + 255) & ~(size_t)255;
    return p;
  };
  int*   mode      = (int*)alloc(sizeof(int));
  int*   bucketCnt = (int*)alloc(NBMAX * 4);
  int*   bucketOff = (int*)alloc((NBMAX + 1) * 4);
  int*   bucketCur = (int*)alloc(NBMAX * 4);
  int*   offs      = (int*)alloc((size_t)(n + 1) * 4);
  float* dis       = (float*)alloc((size_t)n * 4);
  int*   csr       = (int*)alloc((size_t)e * 4);
  float* pooled    = (float*)alloc(128 * 4);
  u16*   wp        = (u16*)alloc(3 * 2048 * 8 * 2);
  u16*   xb        = (u16*)alloc((size_t)n * 128 * 2);
  u16*   tmpb      = (u16*)alloc((size_t)n * 128 * 2);
  u16*   houtb     = (u16*)alloc((size_t)n * 128 * 2);
  int*   pairBuf   = (int*)tmpb;  // alias: pairs consumed before first GEMM

  k_detect<<<1, 256, 0, stream>>>(ei, mode, e);
  k_zero<<<1, 256, 0, stream>>>(bucketCnt, pooled, nb);
  b_count<<<192, 256, 0, stream>>>(ei, mode, bucketCnt, e, nb);
  b_bscan<<<1, 256, 0, stream>>>(bucketCnt, bucketOff, bucketCur, nb, e);
  b_scatter<<<(e + SCH - 1) / SCH, 256, 0, stream>>>(ei, mode, bucketCur, pairBuf, e, nb);
  b_fine<<<nb, 512, 0, stream>>>(pairBuf, bucketOff, offs, dis, csr, n, e);

  size_t total4 = (size_t)n * 32;  // float4 groups in x
  k_xcvt<<<1024, 256, 0, stream>>>(x, xb, total4);
  k_wpack<<<8, 256, 0, stream>>>(W0, wp);
  k_wpack<<<8, 256, 0, stream>>>(W1, wp + 2048 * 8);
  k_wpack<<<8, 256, 0, stream>>>(W2, wp + 2 * 2048 * 8);

  const float* bs_[3] = {b0, b1, b2};
  const u16* hin = xb;
  int gg = (n + 63) / 64;
  int gn = (n + 3) / 4;
  for (int l = 0; l < 3; ++l) {
    k_gemm_mfma<<<gg, 256, 0, stream>>>(hin, wp + (size_t)l * 2048 * 8, dis, tmpb, n);
    k_gather_bf<<<gn, 256, 0, stream>>>(tmpb, csr, offs, dis, bs_[l], houtb, n);
    hin = houtb;
  }

  k_pool_bf<<<512, 256, 0, stream>>>(houtb, pooled, n);
  k_final<<<1, 32, 0, stream>>>(pooled, Wfc, bfc, (float*)d_out, 1.0f / (float)n);
}